// Round 6
// baseline (1650.771 us; speedup 1.0000x reference)
//
#include <hip/hip_runtime.h>
#include <hip/hip_fp16.h>
#include <math.h>

#define NUV 200000
#define NIV 100000
#define EV  1000000
#define NQV 100000
#define NC  (3 * NIV + 3 * NUV)   // 900000 concatenated degree/bucket counters
#define EV6 (6 * EV)
// bucket layout: [rel0 items][rel1 items][rel2 items][rel0 users][rel1 users][rel2 users]

struct alignas(8) H4 { __half2 a, b; };

// ---------------- fp32 -> fp16 table conversion (both tables) ----------------
__global__ __launch_bounds__(256) void k_tohalf(const float* __restrict__ inu,
                                                const float* __restrict__ ini,
                                                __half* __restrict__ outu,
                                                __half* __restrict__ outi) {
    const int NU4 = NUV * 16;  // float4 groups in user table
    const int NTOT = NU4 + NIV * 16;
    int i = blockIdx.x * 256 + threadIdx.x;
    if (i < NTOT) {
        const float* in = (i < NU4) ? inu : ini;
        __half* out = (i < NU4) ? outu : outi;
        int j = (i < NU4) ? i : (i - NU4);
        float4 v = ((const float4*)in)[j];
        H4 o;
        o.a = __floats2half2_rn(v.x, v.y);
        o.b = __floats2half2_rn(v.z, v.w);
        ((H4*)out)[j] = o;
    }
}

// ---------------- histogram + in-bucket rank (all 3 relations) ---------------
__global__ __launch_bounds__(256) void k_count(const int* __restrict__ e0,
                                               const int* __restrict__ e1,
                                               const int* __restrict__ e2,
                                               int* __restrict__ cnt,
                                               int* __restrict__ rk_i,
                                               int* __restrict__ rk_u) {
    int k = blockIdx.y;
    const int* ed = (k == 0) ? e0 : (k == 1) ? e1 : e2;
    int e = blockIdx.x * 256 + threadIdx.x;
    if (e < EV) {
        int u = ed[e], i = ed[EV + e];
        rk_i[(size_t)k * EV + e] = atomicAdd(&cnt[k * NIV + i], 1);
        rk_u[(size_t)k * EV + e] = atomicAdd(&cnt[3 * NIV + k * NUV + u], 1);
    }
}

// ---------------- scan stage 1 (+ fused 1/sqrt(deg)) -------------------------
__global__ __launch_bounds__(256) void k_scan1(const int* __restrict__ cnt,
                                               int* __restrict__ S,
                                               int* __restrict__ bsum,
                                               float* __restrict__ invs) {
    __shared__ int tmp[256];
    int idx = blockIdx.x * 256 + threadIdx.x;
    int v = (idx < NC) ? cnt[idx] : 0;
    if (idx < NC) invs[idx] = (v > 0) ? (1.0f / sqrtf((float)v)) : 0.0f;
    tmp[threadIdx.x] = v;
    __syncthreads();
    for (int off = 1; off < 256; off <<= 1) {
        int t = (threadIdx.x >= off) ? tmp[threadIdx.x - off] : 0;
        __syncthreads();
        tmp[threadIdx.x] += t;
        __syncthreads();
    }
    if (idx < NC) S[idx] = tmp[threadIdx.x] - v;
    if (threadIdx.x == 255) bsum[blockIdx.x] = tmp[255];
}

// ---------------- scan stage 2: single-wave scan of block sums ---------------
__global__ __launch_bounds__(64) void k_scan2(int* __restrict__ bsum, int nb) {
    int lane = threadIdx.x;
    int carry = 0;
    for (int base = 0; base < nb; base += 64) {
        int i = base + lane;
        int v = (i < nb) ? bsum[i] : 0;
        int orig = v;
        #pragma unroll
        for (int off = 1; off < 64; off <<= 1) {
            int t = __shfl_up(v, off, 64);
            if (lane >= off) v += t;
        }
        if (i < nb) bsum[i] = carry + v - orig;  // exclusive
        carry += __shfl(v, 63, 64);
    }
}

// ---------------- scan stage 3: add block offsets, write sentinel ------------
__global__ __launch_bounds__(256) void k_scan3(int* __restrict__ S,
                                               const int* __restrict__ bsum) {
    int idx = blockIdx.x * 256 + threadIdx.x;
    if (idx < NC) S[idx] += bsum[blockIdx.x];
    if (idx == 0) S[NC] = EV6;
}

// ---------------- fill CSR entries via precomputed ranks (no atomics) --------
__global__ __launch_bounds__(256) void k_fill(const int* __restrict__ e0,
                                              const int* __restrict__ e1,
                                              const int* __restrict__ e2,
                                              const float* __restrict__ invs,
                                              const int* __restrict__ S,
                                              const int* __restrict__ rk_i,
                                              const int* __restrict__ rk_u,
                                              float2* __restrict__ ent) {
    int k = blockIdx.y;
    const int* ed = (k == 0) ? e0 : (k == 1) ? e1 : e2;
    int e = blockIdx.x * 256 + threadIdx.x;
    if (e < EV) {
        int u = ed[e], i = ed[EV + e];
        float nm = invs[k * NIV + i] * invs[3 * NIV + k * NUV + u];
        int p1 = S[k * NIV + i] + rk_i[(size_t)k * EV + e];
        ent[p1] = make_float2(__int_as_float(u), nm);
        int p2 = S[3 * NIV + k * NUV + u] + rk_u[(size_t)k * EV + e];
        ent[p2] = make_float2(__int_as_float(i), nm);
    }
}

// ---------------- fused gather-aggregate + transform + hetero combine --------
// One launch covers both directions. Features are fp16 rows (64 half = 128 B).
// NEW: each wave gathers for ALL 3 relations x its 4 dst nodes concurrently:
// per iteration it issues 12 independent ent loads then 12 independent
// feature-row loads, all UNCONDITIONAL (clamped address, norm=0 when OOB) so
// the compiler batches them (needs ~120 VGPR). One sync round total.
// Transform reads W directly from global (L1/L2-hot); no sW staging.
// MODE 0: relu(max over rel), MODE 1: sum over rel. HOUT: fp16 out else fp32.
template <int MODE, bool HOUT>
__global__ __launch_bounds__(256, 4) void k_agg(const __half* __restrict__ x_i,  // srcs for item-side (users)
                                                const __half* __restrict__ x_u,  // srcs for user-side (items)
                                                const float2* __restrict__ ent,
                                                const int* __restrict__ S,
                                                const float* __restrict__ Wall,  // [6,64,64]
                                                const float* __restrict__ ball,  // [6,64]
                                                void* __restrict__ out_i,
                                                void* __restrict__ out_u) {
    __shared__ float sAcc[3][16 * 68];   // 12.75 KB, stride 68 (pad)
    const int nb_i = NIV / 16;
    bool item_side = blockIdx.x < nb_i;
    const __half* x = item_side ? x_i : x_u;
    const float* Wb = item_side ? Wall : Wall + 3 * 4096;
    const float* bb = item_side ? ball : ball + 192;
    void* outp      = item_side ? out_i : out_u;
    int n_dst       = item_side ? NIV : NUV;
    int seg_base    = item_side ? 0 : 3 * NIV;
    int d0          = (item_side ? blockIdx.x : (blockIdx.x - nb_i)) * 16;

    int wave = threadIdx.x >> 6;
    int lane = threadIdx.x & 63;
    int eg   = lane >> 4;             // edge subgroup 0..3
    int fq   = lane & 15;             // 8-byte column group 0..15 (4 halves)
    int r2 = threadIdx.x >> 4;        // 0..15 row for transform phase
    int g  = threadIdx.x & 15;        // col group (4 cols)

    // segment bounds: sb[k][0..4] = S[idx..idx+4] for this wave's 4 nodes
    int sb[3][5];
    #pragma unroll
    for (int k = 0; k < 3; k++) {
        int idx = seg_base + k * n_dst + d0 + wave * 4;
        #pragma unroll
        for (int j = 0; j < 5; j++) sb[k][j] = S[idx + j];
    }
    int mx = 0;
    #pragma unroll
    for (int k = 0; k < 3; k++)
        #pragma unroll
        for (int n = 0; n < 4; n++) mx = max(mx, sb[k][n + 1] - sb[k][n]);
    int maxit = (mx + 3) >> 2;

    float acc[3][4][4];
    #pragma unroll
    for (int k = 0; k < 3; k++)
        #pragma unroll
        for (int n = 0; n < 4; n++)
            #pragma unroll
            for (int j = 0; j < 4; j++) acc[k][n][j] = 0.f;

    for (int it = 0; it < maxit; it++) {
        int base = (it << 2) + eg;
        // phase 1: 12 independent ent loads (clamped, unconditional)
        float2 ev[3][4];
        #pragma unroll
        for (int k = 0; k < 3; k++)
            #pragma unroll
            for (int n = 0; n < 4; n++) {
                int p = sb[k][n] + base;
                int pc = min(p, EV6 - 1);
                ev[k][n] = ent[pc];
            }
        // phase 2: 12 independent feature-row loads + OOB norm zeroing
        float2 raw[3][4];
        float nm[3][4];
        #pragma unroll
        for (int k = 0; k < 3; k++)
            #pragma unroll
            for (int n = 0; n < 4; n++) {
                int p = sb[k][n] + base;
                nm[k][n] = (p < sb[k][n + 1]) ? ev[k][n].y : 0.f;
                int s = __float_as_int(ev[k][n].x);
                raw[k][n] = *(const float2*)(x + (size_t)s * 64 + fq * 4);
            }
        // phase 3: fma
        #pragma unroll
        for (int k = 0; k < 3; k++)
            #pragma unroll
            for (int n = 0; n < 4; n++) {
                const __half2* h2 = (const __half2*)&raw[k][n];
                float2 f0 = __half22float2(h2[0]);
                float2 f1 = __half22float2(h2[1]);
                acc[k][n][0] = fmaf(f0.x, nm[k][n], acc[k][n][0]);
                acc[k][n][1] = fmaf(f0.y, nm[k][n], acc[k][n][1]);
                acc[k][n][2] = fmaf(f1.x, nm[k][n], acc[k][n][2]);
                acc[k][n][3] = fmaf(f1.y, nm[k][n], acc[k][n][3]);
            }
    }
    // reduce across the 4 edge-subgroups (lanes l, l^16, l^32, l^48)
    #pragma unroll
    for (int k = 0; k < 3; k++)
        #pragma unroll
        for (int n = 0; n < 4; n++) {
            #pragma unroll
            for (int j = 0; j < 4; j++) {
                acc[k][n][j] += __shfl_xor(acc[k][n][j], 16, 64);
                acc[k][n][j] += __shfl_xor(acc[k][n][j], 32, 64);
            }
            if (lane < 16)
                *(float4*)&sAcc[k][(wave * 4 + n) * 68 + fq * 4] =
                    make_float4(acc[k][n][0], acc[k][n][1], acc[k][n][2], acc[k][n][3]);
        }
    __syncthreads();

    // transform per relation (W from global, L1/L2-hot) + combine
    float4 res = make_float4(0.f, 0.f, 0.f, 0.f);
    #pragma unroll
    for (int k = 0; k < 3; k++) {
        const float* Wk = Wb + (size_t)k * 4096;
        float4 y = *(const float4*)&bb[k * 64 + g * 4];
        #pragma unroll
        for (int c = 0; c < 64; c++) {
            float a = sAcc[k][r2 * 68 + c];
            float4 w = *(const float4*)&Wk[c * 64 + g * 4];
            y.x = fmaf(a, w.x, y.x);
            y.y = fmaf(a, w.y, y.y);
            y.z = fmaf(a, w.z, y.z);
            y.w = fmaf(a, w.w, y.w);
        }
        if (k == 0) {
            res = y;
        } else if (MODE == 0) {
            res.x = fmaxf(res.x, y.x); res.y = fmaxf(res.y, y.y);
            res.z = fmaxf(res.z, y.z); res.w = fmaxf(res.w, y.w);
        } else {
            res.x += y.x; res.y += y.y; res.z += y.z; res.w += y.w;
        }
    }
    if (MODE == 0) {
        res.x = fmaxf(res.x, 0.f); res.y = fmaxf(res.y, 0.f);
        res.z = fmaxf(res.z, 0.f); res.w = fmaxf(res.w, 0.f);
    }
    if (HOUT) {
        H4 o;
        o.a = __floats2half2_rn(res.x, res.y);
        o.b = __floats2half2_rn(res.z, res.w);
        *(H4*)((__half*)outp + (size_t)(d0 + r2) * 64 + g * 4) = o;
    } else {
        *(float4*)((float*)outp + (size_t)(d0 + r2) * 64 + g * 4) = res;
    }
}

// ---------------- decoder: 16 queries per block, tile GEMM -------------------
__global__ __launch_bounds__(256) void k_decoder(const float* __restrict__ xu,
                                                 const float* __restrict__ xi,
                                                 const int* __restrict__ uids,
                                                 const int* __restrict__ iids,
                                                 const float* __restrict__ w1,
                                                 const float* __restrict__ b1,
                                                 const float* __restrict__ w2,
                                                 const float* __restrict__ b2,
                                                 float* __restrict__ out) {
    __shared__ float sW1[128 * 64];   // 32 KB
    __shared__ float sE[16 * 132];    // 16 gathered 128-dim rows, padded
    __shared__ float sH[16 * 68];     // hidden after relu, padded
    __shared__ float sW2[64 * 4];
    // stage weights
    {
        const float4* wsrc = (const float4*)w1;
        float4* wdst = (float4*)sW1;
        #pragma unroll
        for (int i = 0; i < 8; i++) wdst[threadIdx.x + 256 * i] = wsrc[threadIdx.x + 256 * i];
        if (threadIdx.x < 64) {
            float4 v = ((const float4*)w2)[threadIdx.x];
            ((float4*)sW2)[threadIdx.x] = v;
        }
    }
    int q0 = blockIdx.x * 16;
    // gather 16 query rows (user 64 + item 64) into sE
    {
        int q = threadIdx.x >> 4;     // 0..15
        int p = threadIdx.x & 15;     // 0..15 float4s
        int uid = uids[q0 + q];
        int iid = iids[q0 + q];
        float4 vu = *(const float4*)&xu[(size_t)uid * 64 + p * 4];
        float4 vi = *(const float4*)&xi[(size_t)iid * 64 + p * 4];
        *(float4*)&sE[q * 132 + p * 4] = vu;
        *(float4*)&sE[q * 132 + 64 + p * 4] = vi;
    }
    __syncthreads();
    // layer 1: h = relu(E @ W1 + b1); thread = (row r, col group g)
    {
        int r = threadIdx.x >> 4;
        int g = threadIdx.x & 15;
        float4 y = *(const float4*)&b1[g * 4];
        #pragma unroll
        for (int c = 0; c < 128; c++) {
            float a = sE[r * 132 + c];
            float4 w = *(const float4*)&sW1[c * 64 + g * 4];
            y.x = fmaf(a, w.x, y.x);
            y.y = fmaf(a, w.y, y.y);
            y.z = fmaf(a, w.z, y.z);
            y.w = fmaf(a, w.w, y.w);
        }
        y.x = fmaxf(y.x, 0.f); y.y = fmaxf(y.y, 0.f);
        y.z = fmaxf(y.z, 0.f); y.w = fmaxf(y.w, 0.f);
        *(float4*)&sH[r * 68 + g * 4] = y;
    }
    __syncthreads();
    // layer 2: out = H @ W2 + b2 ; 64 threads, one (query, out-col) each
    if (threadIdx.x < 64) {
        int q = threadIdx.x >> 2;
        int oc = threadIdx.x & 3;
        float acc = b2[oc];
        #pragma unroll
        for (int c = 0; c < 64; c++)
            acc = fmaf(sH[q * 68 + c], sW2[c * 4 + oc], acc);
        out[(size_t)(q0 + q) * 4 + oc] = acc;
    }
}

extern "C" void kernel_launch(void* const* d_in, const int* in_sizes, int n_in,
                              void* d_out, int out_size, void* d_ws, size_t ws_size,
                              hipStream_t stream) {
    const float* user_emb = (const float*)d_in[0];
    const float* item_emb = (const float*)d_in[1];
    const float* W1 = (const float*)d_in[2];
    const float* b1 = (const float*)d_in[3];
    const float* W2 = (const float*)d_in[4];
    const float* b2 = (const float*)d_in[5];
    const float* dw1 = (const float*)d_in[6];
    const float* db1 = (const float*)d_in[7];
    const float* dw2 = (const float*)d_in[8];
    const float* db2 = (const float*)d_in[9];
    const int* e0 = (const int*)d_in[10];
    const int* e1 = (const int*)d_in[11];
    const int* e2 = (const int*)d_in[12];
    const int* uids = (const int*)d_in[13];
    const int* iids = (const int*)d_in[14];
    float* out = (float*)d_out;
    (void)in_sizes; (void)n_in; (void)out_size; (void)ws_size;

    // workspace layout (all region sizes multiples of 16 B)
    char* base = (char*)d_ws;
    size_t off = 0;
    int*    cnt  = (int*)(base + off);    off += (size_t)NC * 4;
    int*    S    = (int*)(base + off);    off += (size_t)(NC + 8) * 4;
    int*    bsum = (int*)(base + off);    off += (size_t)4096 * 4;
    float*  invs = (float*)(base + off);  off += (size_t)NC * 4;
    int*    rki  = (int*)(base + off);    off += (size_t)3 * EV * 4;
    int*    rku  = (int*)(base + off);    off += (size_t)3 * EV * 4;
    float2* ent  = (float2*)(base + off); off += (size_t)EV6 * 8;
    __half* he_u = (__half*)(base + off); off += (size_t)NUV * 64 * 2;
    __half* he_i = (__half*)(base + off); off += (size_t)NIV * 64 * 2;
    __half* xu1h = (__half*)(base + off); off += (size_t)NUV * 64 * 2;
    __half* xi1h = (__half*)(base + off); off += (size_t)NIV * 64 * 2;
    float*  xu2  = (float*)(base + off);  off += (size_t)NUV * 64 * 4;
    float*  xi2  = (float*)(base + off);  off += (size_t)NIV * 64 * 4;

    const int EB  = (EV + 255) / 256;       // 3907
    const int SB1 = (NC + 255) / 256;       // 3516
    const int AGGB = NIV / 16 + NUV / 16;   // 18750
    const int THB = ((NUV + NIV) * 16 + 255) / 256;

    // ---- fp16 feature tables ----
    k_tohalf<<<THB, 256, 0, stream>>>(user_emb, item_emb, he_u, he_i);

    // ---- CSR build ----
    hipMemsetAsync(cnt, 0, (size_t)NC * 4, stream);
    k_count<<<dim3(EB, 3), 256, 0, stream>>>(e0, e1, e2, cnt, rki, rku);
    k_scan1<<<SB1, 256, 0, stream>>>(cnt, S, bsum, invs);
    k_scan2<<<1, 64, 0, stream>>>(bsum, SB1);
    k_scan3<<<SB1, 256, 0, stream>>>(S, bsum);
    k_fill<<<dim3(EB, 3), 256, 0, stream>>>(e0, e1, e2, invs, S, rki, rku, ent);

    // ---- layer 1 (max across relations, then relu): both directions ----
    k_agg<0, true><<<AGGB, 256, 0, stream>>>(he_u, he_i, ent, S, W1, b1, xi1h, xu1h);
    // ---- layer 2 (sum across relations): both directions ----
    k_agg<1, false><<<AGGB, 256, 0, stream>>>(xu1h, xi1h, ent, S, W2, b2, xi2, xu2);

    // ---- decoder ----
    k_decoder<<<NQV / 16, 256, 0, stream>>>(xu2, xi2, uids, iids,
                                            dw1, db1, dw2, db2, out);
}

// Round 7
// 1604.380 us; speedup vs baseline: 1.0289x; 1.0289x over previous
//
#include <hip/hip_runtime.h>
#include <hip/hip_fp16.h>
#include <math.h>

#define NUV 200000
#define NIV 100000
#define EV  1000000
#define NQV 100000
#define NC  (3 * NIV + 3 * NUV)   // 900000 concatenated degree/bucket counters
#define EV6 (6 * EV)
// bucket layout: [rel0 items][rel1 items][rel2 items][rel0 users][rel1 users][rel2 users]

struct alignas(8) H4 { __half2 a, b; };

// ---------------- fp32 -> fp16 table conversion (both tables) ----------------
__global__ __launch_bounds__(256) void k_tohalf(const float* __restrict__ inu,
                                                const float* __restrict__ ini,
                                                __half* __restrict__ outu,
                                                __half* __restrict__ outi) {
    const int NU4 = NUV * 16;  // float4 groups in user table
    const int NTOT = NU4 + NIV * 16;
    int i = blockIdx.x * 256 + threadIdx.x;
    if (i < NTOT) {
        const float* in = (i < NU4) ? inu : ini;
        __half* out = (i < NU4) ? outu : outi;
        int j = (i < NU4) ? i : (i - NU4);
        float4 v = ((const float4*)in)[j];
        H4 o;
        o.a = __floats2half2_rn(v.x, v.y);
        o.b = __floats2half2_rn(v.z, v.w);
        ((H4*)out)[j] = o;
    }
}

// ---------------- histogram + in-bucket rank (all 3 relations) ---------------
__global__ __launch_bounds__(256) void k_count(const int* __restrict__ e0,
                                               const int* __restrict__ e1,
                                               const int* __restrict__ e2,
                                               int* __restrict__ cnt,
                                               int* __restrict__ rk_i,
                                               int* __restrict__ rk_u) {
    int k = blockIdx.y;
    const int* ed = (k == 0) ? e0 : (k == 1) ? e1 : e2;
    int e = blockIdx.x * 256 + threadIdx.x;
    if (e < EV) {
        int u = ed[e], i = ed[EV + e];
        rk_i[(size_t)k * EV + e] = atomicAdd(&cnt[k * NIV + i], 1);
        rk_u[(size_t)k * EV + e] = atomicAdd(&cnt[3 * NIV + k * NUV + u], 1);
    }
}

// ---------------- scan stage 1 (+ fused 1/sqrt(deg)) -------------------------
__global__ __launch_bounds__(256) void k_scan1(const int* __restrict__ cnt,
                                               int* __restrict__ S,
                                               int* __restrict__ bsum,
                                               float* __restrict__ invs) {
    __shared__ int tmp[256];
    int idx = blockIdx.x * 256 + threadIdx.x;
    int v = (idx < NC) ? cnt[idx] : 0;
    if (idx < NC) invs[idx] = (v > 0) ? (1.0f / sqrtf((float)v)) : 0.0f;
    tmp[threadIdx.x] = v;
    __syncthreads();
    for (int off = 1; off < 256; off <<= 1) {
        int t = (threadIdx.x >= off) ? tmp[threadIdx.x - off] : 0;
        __syncthreads();
        tmp[threadIdx.x] += t;
        __syncthreads();
    }
    if (idx < NC) S[idx] = tmp[threadIdx.x] - v;
    if (threadIdx.x == 255) bsum[blockIdx.x] = tmp[255];
}

// ---------------- scan stage 2: single-wave scan of block sums ---------------
__global__ __launch_bounds__(64) void k_scan2(int* __restrict__ bsum, int nb) {
    int lane = threadIdx.x;
    int carry = 0;
    for (int base = 0; base < nb; base += 64) {
        int i = base + lane;
        int v = (i < nb) ? bsum[i] : 0;
        int orig = v;
        #pragma unroll
        for (int off = 1; off < 64; off <<= 1) {
            int t = __shfl_up(v, off, 64);
            if (lane >= off) v += t;
        }
        if (i < nb) bsum[i] = carry + v - orig;  // exclusive
        carry += __shfl(v, 63, 64);
    }
}

// ---------------- scan stage 3: add block offsets, write sentinel ------------
__global__ __launch_bounds__(256) void k_scan3(int* __restrict__ S,
                                               const int* __restrict__ bsum) {
    int idx = blockIdx.x * 256 + threadIdx.x;
    if (idx < NC) S[idx] += bsum[blockIdx.x];
    if (idx == 0) S[NC] = EV6;
}

// ---------------- fill CSR entries via precomputed ranks (no atomics) --------
__global__ __launch_bounds__(256) void k_fill(const int* __restrict__ e0,
                                              const int* __restrict__ e1,
                                              const int* __restrict__ e2,
                                              const float* __restrict__ invs,
                                              const int* __restrict__ S,
                                              const int* __restrict__ rk_i,
                                              const int* __restrict__ rk_u,
                                              float2* __restrict__ ent) {
    int k = blockIdx.y;
    const int* ed = (k == 0) ? e0 : (k == 1) ? e1 : e2;
    int e = blockIdx.x * 256 + threadIdx.x;
    if (e < EV) {
        int u = ed[e], i = ed[EV + e];
        float nm = invs[k * NIV + i] * invs[3 * NIV + k * NUV + u];
        int p1 = S[k * NIV + i] + rk_i[(size_t)k * EV + e];
        ent[p1] = make_float2(__int_as_float(u), nm);
        int p2 = S[3 * NIV + k * NUV + u] + rk_u[(size_t)k * EV + e];
        ent[p2] = make_float2(__int_as_float(i), nm);
    }
}

// ---------------- fused gather-aggregate + transform + hetero combine --------
// One launch covers both directions (blocks XCD-chunk-swizzled).
// Gather: block owns 16 dst nodes -> 48 (rel,node) tasks; 32 8-lane subgroups
// pull tasks from an LDS queue. Lane owns a 16B slice of the 128B fp16 row and
// accumulates 8 fp32 IN-LANE (no shuffles). Per iteration a subgroup runs 4
// independent ent->row chains; a wave keeps ~32 rows in flight at ~60 VGPR.
// One __syncthreads; then 256 threads = 16 rows x 16 col-groups compute
// y_k = acc_k @ W_k + b_k (W from global, L1-hot) and combine across k.
// MODE 0: relu(max over rel), MODE 1: sum over rel. HOUT: fp16 out else fp32.
template <int MODE, bool HOUT>
__global__ __launch_bounds__(256, 4) void k_agg(const __half* __restrict__ x_i,  // srcs for item-side (users)
                                                const __half* __restrict__ x_u,  // srcs for user-side (items)
                                                const float2* __restrict__ ent,
                                                const int* __restrict__ S,
                                                const float* __restrict__ Wall,  // [6,64,64]
                                                const float* __restrict__ ball,  // [6,64]
                                                void* __restrict__ out_i,
                                                void* __restrict__ out_u) {
    __shared__ float sAcc[3][16][68];   // ~13 KB, stride 68 (bank pad)
    __shared__ int nextT;

    // bijective XCD-chunk swizzle: adjacent work -> same XCD L2
    const int NWG = NIV / 16 + NUV / 16;      // 18750
    const int q = NWG / 8, r = NWG % 8;       // 2343, 6
    int xcd = blockIdx.x % 8, pos = blockIdx.x / 8;
    int wg = (xcd < r) ? (xcd * (q + 1) + pos) : (r * (q + 1) + (xcd - r) * q + pos);

    const int nb_i = NIV / 16;
    bool item_side = wg < nb_i;
    const __half* x = item_side ? x_i : x_u;
    const float* Wb = item_side ? Wall : Wall + 3 * 4096;
    const float* bb = item_side ? ball : ball + 192;
    void* outp      = item_side ? out_i : out_u;
    int n_dst       = item_side ? NIV : NUV;
    int seg_base    = item_side ? 0 : 3 * NIV;
    int d0          = (item_side ? wg : (wg - nb_i)) * 16;

    if (threadIdx.x == 0) nextT = 32;
    __syncthreads();

    int sgid = threadIdx.x >> 3;          // 0..31 subgroup id in block
    int ls   = threadIdx.x & 7;           // lane in subgroup: owns cols ls*8..+8
    int lane = threadIdx.x & 63;

    int task = sgid;
    while (task < 48) {
        int rel = task >> 4, node = task & 15;
        int idx = seg_base + rel * n_dst + d0 + node;
        int st = S[idx], en = S[idx + 1];

        float4 a0 = make_float4(0.f, 0.f, 0.f, 0.f);
        float4 a1 = make_float4(0.f, 0.f, 0.f, 0.f);
        for (int base = st; base < en; base += 4) {
            // 4 masked ent loads (OOB -> s=0 row, nm=0: L1-hot, no traffic)
            float2 ee[4];
            #pragma unroll
            for (int j = 0; j < 4; j++) {
                float2 e = make_float2(0.0f, 0.0f);
                if (base + j < en) e = ent[base + j];
                ee[j] = e;
            }
            // 4 independent row loads (unconditional, s=0 fallback)
            float4 rr[4];
            #pragma unroll
            for (int j = 0; j < 4; j++) {
                int s = __float_as_int(ee[j].x);
                rr[j] = *(const float4*)(x + (size_t)s * 64 + ls * 8);
            }
            // fma
            #pragma unroll
            for (int j = 0; j < 4; j++) {
                float nm = ee[j].y;
                const __half2* h2 = (const __half2*)&rr[j];
                float2 f0 = __half22float2(h2[0]);
                float2 f1 = __half22float2(h2[1]);
                float2 f2 = __half22float2(h2[2]);
                float2 f3 = __half22float2(h2[3]);
                a0.x = fmaf(f0.x, nm, a0.x);
                a0.y = fmaf(f0.y, nm, a0.y);
                a0.z = fmaf(f1.x, nm, a0.z);
                a0.w = fmaf(f1.y, nm, a0.w);
                a1.x = fmaf(f2.x, nm, a1.x);
                a1.y = fmaf(f2.y, nm, a1.y);
                a1.z = fmaf(f3.x, nm, a1.z);
                a1.w = fmaf(f3.y, nm, a1.w);
            }
        }
        *(float4*)&sAcc[rel][node][ls * 8]     = a0;
        *(float4*)&sAcc[rel][node][ls * 8 + 4] = a1;

        // grab next task (subgroup leader), broadcast within subgroup
        int nt = 0;
        if (ls == 0) nt = atomicAdd(&nextT, 1);
        nt = __shfl(nt, lane & 56, 64);
        task = nt;
    }
    __syncthreads();

    // transform per relation (W from global, L1/L2-hot) + combine
    int r2 = threadIdx.x >> 4;        // 0..15 row
    int g  = threadIdx.x & 15;        // col group (4 cols)
    float4 res = make_float4(0.f, 0.f, 0.f, 0.f);
    #pragma unroll
    for (int k = 0; k < 3; k++) {
        const float* Wk = Wb + (size_t)k * 4096;
        float4 y = *(const float4*)&bb[k * 64 + g * 4];
        #pragma unroll
        for (int c = 0; c < 64; c++) {
            float a = sAcc[k][r2][c];
            float4 w = *(const float4*)&Wk[c * 64 + g * 4];
            y.x = fmaf(a, w.x, y.x);
            y.y = fmaf(a, w.y, y.y);
            y.z = fmaf(a, w.z, y.z);
            y.w = fmaf(a, w.w, y.w);
        }
        if (k == 0) {
            res = y;
        } else if (MODE == 0) {
            res.x = fmaxf(res.x, y.x); res.y = fmaxf(res.y, y.y);
            res.z = fmaxf(res.z, y.z); res.w = fmaxf(res.w, y.w);
        } else {
            res.x += y.x; res.y += y.y; res.z += y.z; res.w += y.w;
        }
    }
    if (MODE == 0) {
        res.x = fmaxf(res.x, 0.f); res.y = fmaxf(res.y, 0.f);
        res.z = fmaxf(res.z, 0.f); res.w = fmaxf(res.w, 0.f);
    }
    if (HOUT) {
        H4 o;
        o.a = __floats2half2_rn(res.x, res.y);
        o.b = __floats2half2_rn(res.z, res.w);
        *(H4*)((__half*)outp + (size_t)(d0 + r2) * 64 + g * 4) = o;
    } else {
        *(float4*)((float*)outp + (size_t)(d0 + r2) * 64 + g * 4) = res;
    }
}

// ---------------- decoder: 16 queries per block, tile GEMM -------------------
__global__ __launch_bounds__(256) void k_decoder(const float* __restrict__ xu,
                                                 const float* __restrict__ xi,
                                                 const int* __restrict__ uids,
                                                 const int* __restrict__ iids,
                                                 const float* __restrict__ w1,
                                                 const float* __restrict__ b1,
                                                 const float* __restrict__ w2,
                                                 const float* __restrict__ b2,
                                                 float* __restrict__ out) {
    __shared__ float sW1[128 * 64];   // 32 KB
    __shared__ float sE[16 * 132];    // 16 gathered 128-dim rows, padded
    __shared__ float sH[16 * 68];     // hidden after relu, padded
    __shared__ float sW2[64 * 4];
    // stage weights
    {
        const float4* wsrc = (const float4*)w1;
        float4* wdst = (float4*)sW1;
        #pragma unroll
        for (int i = 0; i < 8; i++) wdst[threadIdx.x + 256 * i] = wsrc[threadIdx.x + 256 * i];
        if (threadIdx.x < 64) {
            float4 v = ((const float4*)w2)[threadIdx.x];
            ((float4*)sW2)[threadIdx.x] = v;
        }
    }
    int q0 = blockIdx.x * 16;
    // gather 16 query rows (user 64 + item 64) into sE
    {
        int q = threadIdx.x >> 4;     // 0..15
        int p = threadIdx.x & 15;     // 0..15 float4s
        int uid = uids[q0 + q];
        int iid = iids[q0 + q];
        float4 vu = *(const float4*)&xu[(size_t)uid * 64 + p * 4];
        float4 vi = *(const float4*)&xi[(size_t)iid * 64 + p * 4];
        *(float4*)&sE[q * 132 + p * 4] = vu;
        *(float4*)&sE[q * 132 + 64 + p * 4] = vi;
    }
    __syncthreads();
    // layer 1: h = relu(E @ W1 + b1); thread = (row r, col group g)
    {
        int r = threadIdx.x >> 4;
        int g = threadIdx.x & 15;
        float4 y = *(const float4*)&b1[g * 4];
        #pragma unroll
        for (int c = 0; c < 128; c++) {
            float a = sE[r * 132 + c];
            float4 w = *(const float4*)&sW1[c * 64 + g * 4];
            y.x = fmaf(a, w.x, y.x);
            y.y = fmaf(a, w.y, y.y);
            y.z = fmaf(a, w.z, y.z);
            y.w = fmaf(a, w.w, y.w);
        }
        y.x = fmaxf(y.x, 0.f); y.y = fmaxf(y.y, 0.f);
        y.z = fmaxf(y.z, 0.f); y.w = fmaxf(y.w, 0.f);
        *(float4*)&sH[r * 68 + g * 4] = y;
    }
    __syncthreads();
    // layer 2: out = H @ W2 + b2 ; 64 threads, one (query, out-col) each
    if (threadIdx.x < 64) {
        int q = threadIdx.x >> 2;
        int oc = threadIdx.x & 3;
        float acc = b2[oc];
        #pragma unroll
        for (int c = 0; c < 64; c++)
            acc = fmaf(sH[q * 68 + c], sW2[c * 4 + oc], acc);
        out[(size_t)(q0 + q) * 4 + oc] = acc;
    }
}

extern "C" void kernel_launch(void* const* d_in, const int* in_sizes, int n_in,
                              void* d_out, int out_size, void* d_ws, size_t ws_size,
                              hipStream_t stream) {
    const float* user_emb = (const float*)d_in[0];
    const float* item_emb = (const float*)d_in[1];
    const float* W1 = (const float*)d_in[2];
    const float* b1 = (const float*)d_in[3];
    const float* W2 = (const float*)d_in[4];
    const float* b2 = (const float*)d_in[5];
    const float* dw1 = (const float*)d_in[6];
    const float* db1 = (const float*)d_in[7];
    const float* dw2 = (const float*)d_in[8];
    const float* db2 = (const float*)d_in[9];
    const int* e0 = (const int*)d_in[10];
    const int* e1 = (const int*)d_in[11];
    const int* e2 = (const int*)d_in[12];
    const int* uids = (const int*)d_in[13];
    const int* iids = (const int*)d_in[14];
    float* out = (float*)d_out;
    (void)in_sizes; (void)n_in; (void)out_size; (void)ws_size;

    // workspace layout (all region sizes multiples of 16 B)
    char* base = (char*)d_ws;
    size_t off = 0;
    int*    cnt  = (int*)(base + off);    off += (size_t)NC * 4;
    int*    S    = (int*)(base + off);    off += (size_t)(NC + 8) * 4;
    int*    bsum = (int*)(base + off);    off += (size_t)4096 * 4;
    float*  invs = (float*)(base + off);  off += (size_t)NC * 4;
    int*    rki  = (int*)(base + off);    off += (size_t)3 * EV * 4;
    int*    rku  = (int*)(base + off);    off += (size_t)3 * EV * 4;
    float2* ent  = (float2*)(base + off); off += (size_t)EV6 * 8;
    __half* he_u = (__half*)(base + off); off += (size_t)NUV * 64 * 2;
    __half* he_i = (__half*)(base + off); off += (size_t)NIV * 64 * 2;
    __half* xu1h = (__half*)(base + off); off += (size_t)NUV * 64 * 2;
    __half* xi1h = (__half*)(base + off); off += (size_t)NIV * 64 * 2;
    float*  xu2  = (float*)(base + off);  off += (size_t)NUV * 64 * 4;
    float*  xi2  = (float*)(base + off);  off += (size_t)NIV * 64 * 4;

    const int EB  = (EV + 255) / 256;       // 3907
    const int SB1 = (NC + 255) / 256;       // 3516
    const int AGGB = NIV / 16 + NUV / 16;   // 18750
    const int THB = ((NUV + NIV) * 16 + 255) / 256;

    // ---- fp16 feature tables ----
    k_tohalf<<<THB, 256, 0, stream>>>(user_emb, item_emb, he_u, he_i);

    // ---- CSR build ----
    hipMemsetAsync(cnt, 0, (size_t)NC * 4, stream);
    k_count<<<dim3(EB, 3), 256, 0, stream>>>(e0, e1, e2, cnt, rki, rku);
    k_scan1<<<SB1, 256, 0, stream>>>(cnt, S, bsum, invs);
    k_scan2<<<1, 64, 0, stream>>>(bsum, SB1);
    k_scan3<<<SB1, 256, 0, stream>>>(S, bsum);
    k_fill<<<dim3(EB, 3), 256, 0, stream>>>(e0, e1, e2, invs, S, rki, rku, ent);

    // ---- layer 1 (max across relations, then relu): both directions ----
    k_agg<0, true><<<AGGB, 256, 0, stream>>>(he_u, he_i, ent, S, W1, b1, xi1h, xu1h);
    // ---- layer 2 (sum across relations): both directions ----
    k_agg<1, false><<<AGGB, 256, 0, stream>>>(xu1h, xi1h, ent, S, W2, b2, xi2, xu2);

    // ---- decoder ----
    k_decoder<<<NQV / 16, 256, 0, stream>>>(xu2, xi2, uids, iids,
                                            dw1, db1, dw2, db2, out);
}